// Round 5
// baseline (717.724 us; speedup 1.0000x reference)
//
#include <hip/hip_runtime.h>

// Capsule routing on MI355X — single fused kernel.
// Identity: softmax over the capsule axis followed by a sum over that axis is
// identically 1 -> the routing loop is dead code and
//   out[b, o] = sum_i ( sum_t x[b,t,i] ) * W[i, o]
// R4 analysis: kernels sum to ~50 us but total is 74.6 -> ~20+ us is graph
// node/launch overhead. Fix: ONE kernel, 2048 co-resident blocks, manual
// device-scope grid barriers (counters in d_ws, zeroed by a leading memset).
//
//   phase 1: colsum x -> part[64][32][1024]   (HBM-bound, ~40 us)
//   barrier
//   phase 2: part -> xs[32][1024] (128 blks) + zero out (32 blks)
//   barrier
//   phase 3: xs @ W -> out (256 blks, LDS xs, XCD-aligned W, 4 atomics/out)

#define BATCH   32
#define TLEN    2048
#define DIN     1024
#define DOUT    2048            // NUM_CAPSULE * DIM_CAPSULE
#define NCHUNK  64
#define RPC     (TLEN / NCHUNK) // 32 rows per chunk
#define GRID    2048
#define BLK     256

typedef float fv4 __attribute__((ext_vector_type(4)));

#define PART_ELEMS ((size_t)NCHUNK * BATCH * DIN)   // 2M floats = 8 MB
#define XS_ELEMS   ((size_t)BATCH * DIN)            // 32K floats = 128 KB
#define CNT_OFF_BYTES ((PART_ELEMS + XS_ELEMS) * sizeof(float))

__device__ __forceinline__ void grid_barrier(unsigned* cnt, unsigned target)
{
    __syncthreads();
    if (threadIdx.x == 0) {
        __threadfence();  // agent-scope release of prior global writes
        __hip_atomic_fetch_add(cnt, 1u, __ATOMIC_ACQ_REL, __HIP_MEMORY_SCOPE_AGENT);
        unsigned guard = 0;
        while (__hip_atomic_load(cnt, __ATOMIC_ACQUIRE, __HIP_MEMORY_SCOPE_AGENT) < target) {
            __builtin_amdgcn_s_sleep(8);
            if (++guard > 4000000u) break;  // failsafe: degrade to wrong answer, never hang
        }
        __threadfence();  // agent-scope acquire side
    }
    __syncthreads();
}

__global__ __launch_bounds__(BLK, 8) void capsule_fused(
    const float* __restrict__ x, const float* __restrict__ W,
    float* __restrict__ out, float* __restrict__ ws,
    unsigned* __restrict__ cnt)
{
    const int bid = blockIdx.x;
    const int tx  = threadIdx.x;
    float* part = ws;
    float* xs   = ws + PART_ELEMS;

    // ---------------- phase 1: column-sum of x over T ----------------
    {
        const int chunk = bid >> 5;   // 0..63
        const int b     = bid & 31;
        const fv4* base = reinterpret_cast<const fv4*>(
            x + (size_t)b * TLEN * DIN + (size_t)chunk * RPC * DIN) + tx;

        fv4 a0 = {0.f, 0.f, 0.f, 0.f};
        fv4 a1 = {0.f, 0.f, 0.f, 0.f};
#pragma unroll 4
        for (int r = 0; r < RPC; r += 2) {
            fv4 v0 = __builtin_nontemporal_load(&base[(size_t)r       * (DIN / 4)]);
            fv4 v1 = __builtin_nontemporal_load(&base[(size_t)(r + 1) * (DIN / 4)]);
            a0 += v0;
            a1 += v1;
        }
        a0 += a1;
        reinterpret_cast<fv4*>(part + ((size_t)chunk * BATCH + b) * DIN)[tx] = a0;
    }

    grid_barrier(&cnt[0], GRID);

    // ---------------- phase 2: reduce part -> xs; zero out ----------------
    if (bid < 128) {
        const int seg = bid >> 5;     // 0..3
        const int b   = bid & 31;
        const int i   = seg * 256 + tx;
        float acc = 0.f;
#pragma unroll 8
        for (int c = 0; c < NCHUNK; ++c)
            acc += part[((size_t)c * BATCH + b) * DIN + i];
        xs[(size_t)b * DIN + i] = acc;
    } else if (bid < 160) {
        const int base = (bid - 128) * 2048 + tx;  // out = 65536 floats
#pragma unroll
        for (int j = 0; j < 8; ++j)
            out[base + j * 256] = 0.f;
    }

    grid_barrier(&cnt[1], GRID);

    // ---------------- phase 3: out[b,o] += xs[b,:] . W[:,o] ----------------
    // 256 blocks: cb = bid&7 (256-col W slice, XCD-aligned -> 1 MB W per XCD
    // L2-resident), bg = 4 batches, iq = 256-i segment. 4 atomics/output.
    if (bid < 256) {
        __shared__ float xls[4][256];  // 4 KB
        const int cb = bid & 7;
        const int bg = (bid >> 3) & 7;
        const int iq = bid >> 6;       // 0..3
        const int i0 = iq * 256;

        {
            const int bb = tx >> 6;    // 0..3
            const int k  = tx & 63;
#pragma unroll
            for (int j = 0; j < 4; ++j)
                xls[bb][k + j * 64] =
                    xs[(size_t)(bg * 4 + bb) * DIN + i0 + k + j * 64];
        }
        __syncthreads();

        const int o = cb * 256 + tx;
        const float* wp = W + (size_t)i0 * DOUT + o;
        float a0 = 0.f, a1 = 0.f, a2 = 0.f, a3 = 0.f;
#pragma unroll 8
        for (int k = 0; k < 256; ++k) {
            const float w = wp[(size_t)k * DOUT];
            a0 += xls[0][k] * w;
            a1 += xls[1][k] * w;
            a2 += xls[2][k] * w;
            a3 += xls[3][k] * w;
        }
        atomicAdd(&out[(size_t)(bg * 4 + 0) * DOUT + o], a0);
        atomicAdd(&out[(size_t)(bg * 4 + 1) * DOUT + o], a1);
        atomicAdd(&out[(size_t)(bg * 4 + 2) * DOUT + o], a2);
        atomicAdd(&out[(size_t)(bg * 4 + 3) * DOUT + o], a3);
    }
}

extern "C" void kernel_launch(void* const* d_in, const int* in_sizes, int n_in,
                              void* d_out, int out_size, void* d_ws, size_t ws_size,
                              hipStream_t stream)
{
    const float* x = (const float*)d_in[0];   // (32, 2048, 1024) f32
    const float* W = (const float*)d_in[1];   // (1024, 2048) f32
    float* out = (float*)d_out;               // (32, 32, 64) f32 flat
    float* ws  = (float*)d_ws;
    unsigned* cnt = (unsigned*)((char*)d_ws + CNT_OFF_BYTES);

    // zero the barrier counters (d_ws is poisoned once, never re-poisoned)
    hipMemsetAsync(cnt, 0, 64, stream);

    capsule_fused<<<GRID, BLK, 0, stream>>>(x, W, out, ws, cnt);
}

// Round 6
// 80.403 us; speedup vs baseline: 8.9266x; 8.9266x over previous
//
#include <hip/hip_runtime.h>

// Capsule routing on MI355X — 2-node pipeline.
// Identity: softmax over the capsule axis followed by a sum over that axis is
// identically 1 -> the routing loop is dead code and
//   out[b, o] = sum_i ( sum_t x[b,t,i] ) * W[i, o]
// R5 lesson: manual grid barriers are a coherence disaster (717 us). R4 fit:
// each graph node transition costs ~7 us -> minimize node count instead.
//
//   K1 colsum_partial : x -> part[64][32][1024]            ~45 us (HBM-bound)
//   K23 reduce_matmul : part -> xls (LDS) ; xls @ W -> out ~8-10 us
// No memset, no atomics: every output written exactly once.

#define BATCH   32
#define TLEN    2048
#define DIN     1024
#define DOUT    2048            // NUM_CAPSULE * DIM_CAPSULE
#define NCHUNK  64
#define RPC     (TLEN / NCHUNK) // 32 rows per chunk

typedef float fv4 __attribute__((ext_vector_type(4)));

// ---------------------------------------------------------------------------
// K1: partial column sums of x over T.  (unchanged from R4 — proven)
// grid = (NCHUNK, BATCH) = 2048 blocks, 256 threads -> 32 waves/CU (max occ).
// ---------------------------------------------------------------------------
__global__ __launch_bounds__(256) void colsum_partial(
    const float* __restrict__ x, float* __restrict__ part)
{
    const int chunk = blockIdx.x;
    const int b     = blockIdx.y;
    const int tx    = threadIdx.x;

    const float4* base = reinterpret_cast<const float4*>(
        x + (size_t)b * TLEN * DIN + (size_t)chunk * RPC * DIN) + tx;

    float4 a0 = make_float4(0.f, 0.f, 0.f, 0.f);
    float4 a1 = make_float4(0.f, 0.f, 0.f, 0.f);
#pragma unroll 8
    for (int r = 0; r < RPC; r += 2) {
        float4 v0 = base[(size_t)r       * (DIN / 4)];
        float4 v1 = base[(size_t)(r + 1) * (DIN / 4)];
        a0.x += v0.x; a0.y += v0.y; a0.z += v0.z; a0.w += v0.w;
        a1.x += v1.x; a1.y += v1.y; a1.z += v1.z; a1.w += v1.w;
    }
    a0.x += a1.x; a0.y += a1.y; a0.z += a1.z; a0.w += a1.w;

    reinterpret_cast<float4*>(part + ((size_t)chunk * BATCH + b) * DIN)[tx] = a0;
}

// ---------------------------------------------------------------------------
// K23: fused chunk-reduce + matmul.
// grid = 64 blocks (cb = bid&7 -> blocks sharing a 1 MB W col-slice land on
// one XCD; bg = bid>>3), 1024 threads (16 waves).
// Phase A: xls[bb][i] = sum_c part[c][bg*4+bb][i]   (float4 loads, 1 MB/block)
// Phase B: out[bg*4+bb][cb*256+ol] = sum_i xls[bb][i] * W[i][o]
//   thread (ol = tx&255, iqq = tx>>8) covers i in [iqq*256, iqq*256+256);
//   per k: 1 coalesced W load + 4 LDS broadcasts + 4 fma. 4-way LDS reduce.
// ---------------------------------------------------------------------------
#define CBW 256   // cols per block
#define BGW 4     // batches per block

__global__ __launch_bounds__(1024) void reduce_matmul(
    const float* __restrict__ part, const float* __restrict__ W,
    float* __restrict__ out)
{
    __shared__ float xls[BGW][DIN];       // 16 KB
    __shared__ float ps[4][BGW][CBW];     // 16 KB

    const int bid = blockIdx.x;
    const int cb  = bid & 7;
    const int bg  = bid >> 3;
    const int tx  = threadIdx.x;

    // ---- Phase A: reduce part -> xls ----
    {
        const int i4 = tx & 255;          // float4 column
        const int bb = tx >> 8;           // 0..3
        const int b  = bg * BGW + bb;
        const fv4* pp = reinterpret_cast<const fv4*>(part + (size_t)b * DIN) + i4;

        fv4 acc = {0.f, 0.f, 0.f, 0.f};
#pragma unroll 8
        for (int c = 0; c < NCHUNK; ++c)
            acc += pp[(size_t)c * BATCH * (DIN / 4)];
        reinterpret_cast<fv4*>(&xls[bb][0])[i4] = acc;
    }
    __syncthreads();

    // ---- Phase B: matmul 256-i segment per thread group ----
    const int ol  = tx & 255;
    const int iqq = tx >> 8;              // 0..3
    const int o   = cb * CBW + ol;
    const int i0  = iqq * 256;

    const float* wp = W + (size_t)i0 * DOUT + o;
    float a0 = 0.f, a1 = 0.f, a2 = 0.f, a3 = 0.f;
#pragma unroll 8
    for (int k = 0; k < 256; ++k) {
        const float w = wp[(size_t)k * DOUT];
        const int i = i0 + k;
        a0 += xls[0][i] * w;
        a1 += xls[1][i] * w;
        a2 += xls[2][i] * w;
        a3 += xls[3][i] * w;
    }
    ps[iqq][0][ol] = a0;
    ps[iqq][1][ol] = a1;
    ps[iqq][2][ol] = a2;
    ps[iqq][3][ol] = a3;
    __syncthreads();

    // ---- combine 4 iqq partials: 1024 threads = (bb = tx>>8, ol) ----
    const int bb2 = tx >> 8;
    float s = ps[0][bb2][ol] + ps[1][bb2][ol] + ps[2][bb2][ol] + ps[3][bb2][ol];
    out[(size_t)(bg * BGW + bb2) * DOUT + o] = s;
}

extern "C" void kernel_launch(void* const* d_in, const int* in_sizes, int n_in,
                              void* d_out, int out_size, void* d_ws, size_t ws_size,
                              hipStream_t stream)
{
    const float* x = (const float*)d_in[0];   // (32, 2048, 1024) f32
    const float* W = (const float*)d_in[1];   // (1024, 2048) f32
    float* out  = (float*)d_out;              // (32, 32, 64) f32 flat
    float* part = (float*)d_ws;               // 8 MB

    dim3 g1(NCHUNK, BATCH);
    colsum_partial<<<g1, 256, 0, stream>>>(x, part);

    reduce_matmul<<<64, 1024, 0, stream>>>(part, W, out);
}

// Round 7
// 73.481 us; speedup vs baseline: 9.7675x; 1.0942x over previous
//
#include <hip/hip_runtime.h>

// Capsule routing on MI355X — 3-node pipeline.
// Identity: softmax over the capsule axis followed by a sum over that axis is
// identically 1 -> the routing loop is dead code and
//   out[b, o] = sum_i ( sum_t x[b,t,i] ) * W[i, o]
// R6 lesson: LDS-broadcast xs reads are an issue storm; keep xs reads on the
// wave-uniform global (s_load) path. This round: R4's proven kernels with the
// memset+atomics node folded away (K3 does full-i dot via per-wave i-split +
// LDS combine) -> 3 nodes total.
//
//   K1 colsum_partial : x -> part[64][32][1024]       (HBM-bound)
//   K2 chunk_reduce   : part -> xs[32][1024], 128 blk (~2.5 us)
//   K3 matmul_small   : xs @ W -> out, 256 blk x 256  (~3 us, no atomics)

#define BATCH   32
#define TLEN    2048
#define DIN     1024
#define DOUT    2048            // NUM_CAPSULE * DIM_CAPSULE
#define NCHUNK  64
#define RPC     (TLEN / NCHUNK) // 32 rows per chunk

// ---------------------------------------------------------------------------
// K1: partial column sums of x over T.  (byte-identical to R4 — proven)
// grid = (NCHUNK, BATCH) = 2048 blocks, 256 threads -> 32 waves/CU.
// ---------------------------------------------------------------------------
__global__ __launch_bounds__(256) void colsum_partial(
    const float* __restrict__ x, float* __restrict__ part)
{
    const int chunk = blockIdx.x;
    const int b     = blockIdx.y;
    const int tx    = threadIdx.x;

    const float4* base = reinterpret_cast<const float4*>(
        x + (size_t)b * TLEN * DIN + (size_t)chunk * RPC * DIN) + tx;

    float4 a0 = make_float4(0.f, 0.f, 0.f, 0.f);
    float4 a1 = make_float4(0.f, 0.f, 0.f, 0.f);
#pragma unroll 8
    for (int r = 0; r < RPC; r += 2) {
        float4 v0 = base[(size_t)r       * (DIN / 4)];
        float4 v1 = base[(size_t)(r + 1) * (DIN / 4)];
        a0.x += v0.x; a0.y += v0.y; a0.z += v0.z; a0.w += v0.w;
        a1.x += v1.x; a1.y += v1.y; a1.z += v1.z; a1.w += v1.w;
    }
    a0.x += a1.x; a0.y += a1.y; a0.z += a1.z; a0.w += a1.w;

    reinterpret_cast<float4*>(part + ((size_t)chunk * BATCH + b) * DIN)[tx] = a0;
}

// ---------------------------------------------------------------------------
// K2: reduce NCHUNK partials -> xs[b][i].  (byte-identical to R4 — proven)
// grid = (DIN/256 = 4 segs, BATCH) = 128 blocks, 256 threads.
// ---------------------------------------------------------------------------
__global__ __launch_bounds__(256) void chunk_reduce(
    const float* __restrict__ part, float* __restrict__ xs)
{
    const int seg = blockIdx.x;
    const int b   = blockIdx.y;
    const int i   = seg * 256 + threadIdx.x;

    float acc = 0.f;
#pragma unroll 8
    for (int c = 0; c < NCHUNK; ++c)
        acc += part[((size_t)c * BATCH + b) * DIN + i];
    xs[(size_t)b * DIN + i] = acc;
}

// ---------------------------------------------------------------------------
// K3: out[b, o] = sum_i xs[b][i] * W[i, o]  — no atomics, no memset.
// grid = (32 cb, 8 bg) = 256 blocks, 256 threads (4 waves).
// Wave w (= tx>>6) covers i in [w*256, w*256+256); lane ol = tx&63 covers
// col o = cb*64+ol. b and i are wave-uniform -> xs reads take the scalar
// s_load path; W loads are coalesced (256 B/wave). Per k: 1 vload + 4 s_load
// + 4 v_fmac. 4-way partial combine via 4 KB LDS; each output written once.
// cb == bid%8-class -> blocks sharing a W col-slice land on one XCD,
// 1 MB W slice L2-hot per XCD.
// ---------------------------------------------------------------------------
__global__ __launch_bounds__(256) void matmul_small(
    const float* __restrict__ xs, const float* __restrict__ W,
    float* __restrict__ out)
{
    __shared__ float ps[4][4][64];   // [iq][bb][ol] = 4 KB

    const int cb = blockIdx.x;   // 0..31
    const int bg = blockIdx.y;   // 0..7
    const int tx = threadIdx.x;
    const int ol = tx & 63;
    const int iq = tx >> 6;      // wave id = i-segment
    const int o  = cb * 64 + ol;
    const int i0 = iq * 256;

    const float* wp = W + (size_t)i0 * DOUT + o;
    const float* x0 = xs + (size_t)(bg * 4 + 0) * DIN + i0;
    const float* x1 = xs + (size_t)(bg * 4 + 1) * DIN + i0;
    const float* x2 = xs + (size_t)(bg * 4 + 2) * DIN + i0;
    const float* x3 = xs + (size_t)(bg * 4 + 3) * DIN + i0;

    float a0 = 0.f, a1 = 0.f, a2 = 0.f, a3 = 0.f;
#pragma unroll 8
    for (int k = 0; k < 256; ++k) {
        const float w = wp[(size_t)k * DOUT];
        a0 += x0[k] * w;
        a1 += x1[k] * w;
        a2 += x2[k] * w;
        a3 += x3[k] * w;
    }
    ps[iq][0][ol] = a0;
    ps[iq][1][ol] = a1;
    ps[iq][2][ol] = a2;
    ps[iq][3][ol] = a3;
    __syncthreads();

    // combine: 256 threads -> (bb = tx>>6, ol); sum 4 iq partials, write once
    const int bb = tx >> 6;
    float s = ps[0][bb][ol] + ps[1][bb][ol] + ps[2][bb][ol] + ps[3][bb][ol];
    out[(size_t)(bg * 4 + bb) * DOUT + cb * 64 + ol] = s;
}

extern "C" void kernel_launch(void* const* d_in, const int* in_sizes, int n_in,
                              void* d_out, int out_size, void* d_ws, size_t ws_size,
                              hipStream_t stream)
{
    const float* x = (const float*)d_in[0];   // (32, 2048, 1024) f32
    const float* W = (const float*)d_in[1];   // (1024, 2048) f32
    float* out  = (float*)d_out;              // (32, 32, 64) f32 flat
    float* part = (float*)d_ws;                                // 8 MB
    float* xs   = (float*)d_ws + (size_t)NCHUNK * BATCH * DIN; // 128 KB

    dim3 g1(NCHUNK, BATCH);
    colsum_partial<<<g1, 256, 0, stream>>>(x, part);

    dim3 g2(DIN / 256, BATCH);
    chunk_reduce<<<g2, 256, 0, stream>>>(part, xs);

    dim3 g3(32, 8);
    matmul_small<<<g3, 256, 0, stream>>>(xs, W, out);
}

// Round 8
// 73.366 us; speedup vs baseline: 9.7828x; 1.0016x over previous
//
#include <hip/hip_runtime.h>

// Capsule routing on MI355X — 3-node pipeline.
// Identity: softmax over the capsule axis followed by a sum over that axis is
// identically 1 -> the routing loop is dead code and
//   out[b, o] = sum_i ( sum_t x[b,t,i] ) * W[i, o]
//
// R7 fit: K1 ~62 us = 4.3 TB/s, VGPR-outstanding-bound (32 waves x ~12 x 16 B
// = 6 KB/CU in flight; need 9.2 KB for 6.3 TB/s at 900 cy latency).
// Fix: global_load_lds streaming — in-flight bytes live in the LDS-DMA queue,
// not VGPRs. Per-wave independent 4-slot ring, depth-3, counted vmcnt(2)
// (never 0 in loop), no __syncthreads (each wave reads only its own segment).
//
//   K1 colsum_lds   : x -> part[64][32][1024]       (HBM-bound, target ~45 us)
//   K2 chunk_reduce : part -> xs[32][1024], 128 blk (~2.5 us)
//   K3 matmul_small : xs @ W -> out, 256 blk x 256  (~3 us, no atomics)

#define BATCH   32
#define TLEN    2048
#define DIN     1024
#define DOUT    2048            // NUM_CAPSULE * DIM_CAPSULE
#define NCHUNK  64
#define RPC     (TLEN / NCHUNK) // 32 rows per chunk

typedef float fv4 __attribute__((ext_vector_type(4)));

// ---------------------------------------------------------------------------
// K1: partial column sums of x over T via LDS-DMA streaming.
// grid = (NCHUNK, BATCH) = 2048 blocks, 256 threads, 16 KB LDS -> 8 blk/CU,
// 32 waves/CU. Wave w streams rows into its own 1 KB segment of a 4-slot
// ring; lane l of wave w reads back exactly the float4 it DMA'd (slot base +
// w*1024B + l*16B == byte offset tx*16) -> zero cross-wave sync.
// Pipeline: prologue issues rows 0..2; iter r waits vmcnt(2) (row r landed),
// accumulates, then issues row r+3 into slot (r+3)&3 (= slot of row r-1,
// whose ds_read completed last iteration; sched_barrier blocks hoisting).
// ---------------------------------------------------------------------------
__global__ __launch_bounds__(256) void colsum_lds(
    const float* __restrict__ x, float* __restrict__ part)
{
    __shared__ float buf[4][DIN];   // 4 row-slots x 4 KB = 16 KB

    const int chunk = blockIdx.x;
    const int b     = blockIdx.y;
    const int tx    = threadIdx.x;

    const float* rowg = x + (size_t)b * TLEN * DIN
                          + (size_t)chunk * RPC * DIN + (size_t)tx * 4;
    // wave-uniform LDS dest base for this wave's 1 KB segment of slot 0
    float* lbase = &buf[0][(tx >> 6) * 256];

#pragma unroll
    for (int r = 0; r < 3; ++r)
        __builtin_amdgcn_global_load_lds(
            (const unsigned int*)(rowg + (size_t)r * DIN),
            (unsigned int*)(lbase + r * DIN), 16, 0, 0);

    fv4 acc = {0.f, 0.f, 0.f, 0.f};
#pragma unroll 4
    for (int r = 0; r < RPC - 3; ++r) {
        asm volatile("s_waitcnt vmcnt(2)" ::: "memory");   // row r landed
        __builtin_amdgcn_sched_barrier(0);
        acc += *reinterpret_cast<const fv4*>(&buf[r & 3][tx * 4]);
        __builtin_amdgcn_global_load_lds(
            (const unsigned int*)(rowg + (size_t)(r + 3) * DIN),
            (unsigned int*)(lbase + ((r + 3) & 3) * DIN), 16, 0, 0);
    }
    // tail: rows 29,30,31 — drain 2 -> 1 -> 0
    asm volatile("s_waitcnt vmcnt(2)" ::: "memory");
    __builtin_amdgcn_sched_barrier(0);
    acc += *reinterpret_cast<const fv4*>(&buf[29 & 3][tx * 4]);
    asm volatile("s_waitcnt vmcnt(1)" ::: "memory");
    __builtin_amdgcn_sched_barrier(0);
    acc += *reinterpret_cast<const fv4*>(&buf[30 & 3][tx * 4]);
    asm volatile("s_waitcnt vmcnt(0)" ::: "memory");
    __builtin_amdgcn_sched_barrier(0);
    acc += *reinterpret_cast<const fv4*>(&buf[31 & 3][tx * 4]);

    reinterpret_cast<fv4*>(part + ((size_t)chunk * BATCH + b) * DIN)[tx] = acc;
}

// ---------------------------------------------------------------------------
// K2: reduce NCHUNK partials -> xs[b][i].  (byte-identical to R7 — proven)
// ---------------------------------------------------------------------------
__global__ __launch_bounds__(256) void chunk_reduce(
    const float* __restrict__ part, float* __restrict__ xs)
{
    const int seg = blockIdx.x;
    const int b   = blockIdx.y;
    const int i   = seg * 256 + threadIdx.x;

    float acc = 0.f;
#pragma unroll 8
    for (int c = 0; c < NCHUNK; ++c)
        acc += part[((size_t)c * BATCH + b) * DIN + i];
    xs[(size_t)b * DIN + i] = acc;
}

// ---------------------------------------------------------------------------
// K3: out[b, o] = sum_i xs[b][i] * W[i, o]  (byte-identical to R7 — proven)
// 256 blocks x 256 threads; per-wave i-segment, scalar xs loads, LDS combine.
// ---------------------------------------------------------------------------
__global__ __launch_bounds__(256) void matmul_small(
    const float* __restrict__ xs, const float* __restrict__ W,
    float* __restrict__ out)
{
    __shared__ float ps[4][4][64];   // [iq][bb][ol] = 4 KB

    const int cb = blockIdx.x;   // 0..31
    const int bg = blockIdx.y;   // 0..7
    const int tx = threadIdx.x;
    const int ol = tx & 63;
    const int iq = tx >> 6;      // wave id = i-segment
    const int o  = cb * 64 + ol;
    const int i0 = iq * 256;

    const float* wp = W + (size_t)i0 * DOUT + o;
    const float* x0 = xs + (size_t)(bg * 4 + 0) * DIN + i0;
    const float* x1 = xs + (size_t)(bg * 4 + 1) * DIN + i0;
    const float* x2 = xs + (size_t)(bg * 4 + 2) * DIN + i0;
    const float* x3 = xs + (size_t)(bg * 4 + 3) * DIN + i0;

    float a0 = 0.f, a1 = 0.f, a2 = 0.f, a3 = 0.f;
#pragma unroll 8
    for (int k = 0; k < 256; ++k) {
        const float w = wp[(size_t)k * DOUT];
        a0 += x0[k] * w;
        a1 += x1[k] * w;
        a2 += x2[k] * w;
        a3 += x3[k] * w;
    }
    ps[iq][0][ol] = a0;
    ps[iq][1][ol] = a1;
    ps[iq][2][ol] = a2;
    ps[iq][3][ol] = a3;
    __syncthreads();

    const int bb = tx >> 6;
    float s = ps[0][bb][ol] + ps[1][bb][ol] + ps[2][bb][ol] + ps[3][bb][ol];
    out[(size_t)(bg * 4 + bb) * DOUT + cb * 64 + ol] = s;
}

extern "C" void kernel_launch(void* const* d_in, const int* in_sizes, int n_in,
                              void* d_out, int out_size, void* d_ws, size_t ws_size,
                              hipStream_t stream)
{
    const float* x = (const float*)d_in[0];   // (32, 2048, 1024) f32
    const float* W = (const float*)d_in[1];   // (1024, 2048) f32
    float* out  = (float*)d_out;              // (32, 32, 64) f32 flat
    float* part = (float*)d_ws;                                // 8 MB
    float* xs   = (float*)d_ws + (size_t)NCHUNK * BATCH * DIN; // 128 KB

    dim3 g1(NCHUNK, BATCH);
    colsum_lds<<<g1, 256, 0, stream>>>(x, part);

    dim3 g2(DIN / 256, BATCH);
    chunk_reduce<<<g2, 256, 0, stream>>>(part, xs);

    dim3 g3(32, 8);
    matmul_small<<<g3, 256, 0, stream>>>(xs, W, out);
}